// Round 10
// baseline (465.511 us; speedup 1.0000x reference)
//
#include <hip/hip_runtime.h>
#include <math.h>

#define EPS 1e-5f

__device__ __forceinline__ float gelu_exact(float x) {
    return 0.5f * x * (1.0f + erff(x * 0.7071067811865476f));
}

// ---- block reductions for finalize (192 threads = 3 waves) ----
__device__ float block_sum(float v, float* red) {
    int lane = threadIdx.x & 63, wid = threadIdx.x >> 6;
#pragma unroll
    for (int off = 32; off > 0; off >>= 1) v += __shfl_down(v, off, 64);
    if (lane == 0) red[wid] = v;
    __syncthreads();
    int nw = ((int)blockDim.x + 63) >> 6;
    float s = red[0];
    for (int w = 1; w < nw; w++) s += red[w];
    __syncthreads();
    return s;
}

__device__ float block_max(float v, float* red) {
    int lane = threadIdx.x & 63, wid = threadIdx.x >> 6;
#pragma unroll
    for (int off = 32; off > 0; off >>= 1) v = fmaxf(v, __shfl_down(v, off, 64));
    if (lane == 0) red[wid] = v;
    __syncthreads();
    int nw = ((int)blockDim.x + 63) >> 6;
    float s = red[0];
    for (int w = 1; w < nw; w++) s = fmaxf(s, red[w]);
    __syncthreads();
    return s;
}

// ---- threefry2x32-20 (JAX PRNG), partitionable scheme (verified round 1) ----
__device__ void threefry2x32(unsigned k0, unsigned k1, unsigned x0, unsigned x1,
                             unsigned& o0, unsigned& o1) {
    unsigned ks[3] = {k0, k1, k0 ^ k1 ^ 0x1BD11BDAu};
    const unsigned rot[2][4] = {{13u, 15u, 26u, 6u}, {17u, 29u, 16u, 24u}};
    x0 += ks[0]; x1 += ks[1];
#pragma unroll
    for (int i = 0; i < 5; i++) {
#pragma unroll
        for (int j = 0; j < 4; j++) {
            unsigned r = rot[i & 1][j];
            x0 += x1;
            x1 = (x1 << r) | (x1 >> (32 - r));
            x1 ^= x0;
        }
        x0 += ks[(i + 1) % 3];
        x1 += ks[(i + 2) % 3] + (unsigned)(i + 1);
    }
    o0 = x0; o1 = x1;
}

__device__ float gumbel_at(int j) {
    unsigned o0, o1;
    threefry2x32(0u, 42u, 0u, (unsigned)j, o0, o1);
    unsigned bits = o0 ^ o1;
    float f = __uint_as_float((bits >> 9) | 0x3F800000u) - 1.0f;  // [0,1)
    float u = fmaxf(f + 1.17549435e-38f, 1.17549435e-38f);
    return -logf(-logf(u));
}

// ---- encode, wave-per-(b,l): 4 waves/block each own one l (round-4). ----
__global__ __launch_bounds__(256) void encode_kernel(
    const float* __restrict__ x_lt, const float* __restrict__ x_st,
    const float* __restrict__ Ws, const float* __restrict__ bs,
    const float* __restrict__ Wt, const float* __restrict__ bt,
    float* __restrict__ e_lt, float* __restrict__ e_st) {
    const int b = blockIdx.y;
    const int w = threadIdx.x >> 6, ln = threadIdx.x & 63;
    const float* x; float* e; int L, l;
    if (blockIdx.x < 128) { x = x_lt; e = e_lt; L = 512; l = blockIdx.x * 4 + w; }
    else { x = x_st; e = e_st; L = 128; l = (blockIdx.x - 128) * 4 + w; }
    __shared__ float xw_all[4][228];
    __shared__ float sm_all[4][20];
    float* xw = xw_all[w];
    float* sm = sm_all[w];
    const float* xb = x + (size_t)b * L * 9;
#pragma unroll
    for (int q = 0; q < 4; q++) {
        int f = ln + 64 * q;
        if (f < 225) {
            int row = f / 9, c = f - row * 9;
            int rr = l - 12 + row;
            rr = rr < 0 ? 0 : (rr >= L ? L - 1 : rr);
            xw[f] = xb[(size_t)rr * 9 + c];
        }
    }
    __syncthreads();
    if (ln < 9) {
        float s = 0.f;
#pragma unroll
        for (int j = 0; j < 25; j++) s += xw[j * 9 + ln];
        float x0 = xb[ln];
        float mm = (s - 25.f * x0) * (1.0f / 25.0f);
        sm[ln] = (xw[108 + ln] - x0) - mm;
        sm[ln + 10] = mm;
    }
    __syncthreads();
    float ysA = bs[ln], ysB = bs[ln + 64];
    float ytA = bt[ln], ytB = bt[ln + 64];
#pragma unroll
    for (int c = 0; c < 9; c++) {
        float sv = sm[c], mv = sm[c + 10];
        ysA += sv * Ws[c * 128 + ln];
        ysB += sv * Ws[c * 128 + ln + 64];
        ytA += mv * Wt[c * 128 + ln];
        ytB += mv * Wt[c * 128 + ln + 64];
    }
    float sa = ysA + ysB, sb2 = ytA + ytB;
#pragma unroll
    for (int off = 32; off > 0; off >>= 1) {
        sa += __shfl_xor(sa, off, 64);
        sb2 += __shfl_xor(sb2, off, 64);
    }
    float ms = sa * (1.0f / 128.0f), mt = sb2 * (1.0f / 128.0f);
    float dA = ysA - ms, dB = ysB - ms;
    float tA = ytA - mt, tB = ytB - mt;
    float qa = dA * dA + dB * dB, qb = tA * tA + tB * tB;
#pragma unroll
    for (int off = 32; off > 0; off >>= 1) {
        qa += __shfl_xor(qa, off, 64);
        qb += __shfl_xor(qb, off, 64);
    }
    float inva = rsqrtf(qa * (1.0f / 128.0f) + EPS);
    float invb = rsqrtf(qb * (1.0f / 128.0f) + EPS);
    float* eo = e + ((size_t)b * L + l) * 128;
    eo[ln] = gelu_exact(dA * inva) + gelu_exact(tA * invb);
    eo[ln + 64] = gelu_exact(dB * inva) + gelu_exact(tB * invb);
}

// ---- Linear -> InstanceNorm -> GELU with BLOCK-SHARED W chunks in LDS
// (round-4 structure, 2-barrier simple staging; no dbuf per R8 lesson). ----
template <int K, int N, int WR, int KC, bool TRANS>
__global__ __launch_bounds__(256) void lbr_wave(
    const float* __restrict__ A, int S, int ABOFF,
    const float* __restrict__ W, const float* __restrict__ bias,
    float* __restrict__ out, int OROWS, int OBOFF) {
    constexpr int CG = N / 4;
    constexpr int SG = 64 / CG;
    constexpr int RW = SG * WR;
    constexpr int MT = 4 * RW;
    constexpr int LOG2MT = (MT == 8) ? 3 : ((MT == 16) ? 4 : 5);
    constexpr int WSZ = KC * N;
    constexpr int ASZ = 4 * RW * K;
    static_assert(WSZ >= MT * (N + 4) || !TRANS, "TRANS tile must fit in W region");
    static_assert((WSZ / 4) % 256 == 0, "W chunk loads must be exact");
    __shared__ __align__(16) float lds[WSZ + ASZ];
    const int t = threadIdx.x;
    const int w = t >> 6, ln = t & 63;
    const int sg = ln / CG;
    const int n0 = (ln % CG) * 4;
    const int b = blockIdx.y;
    const int r0b = blockIdx.x * MT;
    const int r0w = r0b + w * RW;
    float* Wl = lds;
    float* As = lds + WSZ + w * RW * K;
    const float* Ab = A + (size_t)b * ABOFF;
    for (int idx = ln; idx < RW * (K / 4); idx += 64) {
        int rr = idx / (K / 4), kk = idx % (K / 4);
        float4 v = *(const float4*)(Ab + (size_t)(r0w + rr) * S + kk * 4);
        *(float4*)(As + rr * K + kk * 4) = v;
    }
    float4 acc[WR];
    {
        float4 bv = *(const float4*)(bias + n0);
#pragma unroll
        for (int j = 0; j < WR; j++) acc[j] = bv;
    }
    const float* ap = As + (sg * WR) * K;
    for (int kc0 = 0; kc0 < K; kc0 += KC) {
        __syncthreads();
        {
            const float4* wg = (const float4*)(W + (size_t)kc0 * N);
            float4* wl4 = (float4*)Wl;
#pragma unroll
            for (int i = 0; i < WSZ / 4 / 256; i++)
                wl4[t + i * 256] = wg[t + i * 256];
        }
        __syncthreads();
#pragma unroll 2
        for (int k = 0; k < KC; k += 4) {
            const float* wp = Wl + k * N + n0;
            float4 w0 = *(const float4*)(wp);
            float4 w1 = *(const float4*)(wp + N);
            float4 w2 = *(const float4*)(wp + 2 * N);
            float4 w3 = *(const float4*)(wp + 3 * N);
#pragma unroll
            for (int j = 0; j < WR; j++) {
                float4 a4 = *(const float4*)(ap + j * K + kc0 + k);
                acc[j].x += a4.x * w0.x; acc[j].y += a4.x * w0.y;
                acc[j].z += a4.x * w0.z; acc[j].w += a4.x * w0.w;
                acc[j].x += a4.y * w1.x; acc[j].y += a4.y * w1.y;
                acc[j].z += a4.y * w1.z; acc[j].w += a4.y * w1.w;
                acc[j].x += a4.z * w2.x; acc[j].y += a4.z * w2.y;
                acc[j].z += a4.z * w2.z; acc[j].w += a4.z * w2.w;
                acc[j].x += a4.w * w3.x; acc[j].y += a4.w * w3.y;
                acc[j].z += a4.w * w3.z; acc[j].w += a4.w * w3.w;
            }
        }
    }
    float4 res[WR];
#pragma unroll
    for (int j = 0; j < WR; j++) {
        float s = acc[j].x + acc[j].y + acc[j].z + acc[j].w;
#pragma unroll
        for (int off = CG / 2; off > 0; off >>= 1) s += __shfl_xor(s, off, 64);
        float m = s * (1.0f / (float)N);
        float dx = acc[j].x - m, dy = acc[j].y - m, dz = acc[j].z - m, dw = acc[j].w - m;
        float q = dx * dx + dy * dy + dz * dz + dw * dw;
#pragma unroll
        for (int off = CG / 2; off > 0; off >>= 1) q += __shfl_xor(q, off, 64);
        float inv = rsqrtf(q * (1.0f / (float)N) + EPS);
        res[j].x = gelu_exact(dx * inv);
        res[j].y = gelu_exact(dy * inv);
        res[j].z = gelu_exact(dz * inv);
        res[j].w = gelu_exact(dw * inv);
    }
    if constexpr (TRANS) {
        __syncthreads();
#pragma unroll
        for (int j = 0; j < WR; j++) {
            int rl = w * RW + sg * WR + j;
            *(float4*)(lds + rl * (N + 4) + n0) = res[j];
        }
        __syncthreads();
        float* ob = out + (size_t)b * OBOFF + r0b;
        for (int e = t; e < MT * N; e += 256) {
            int r = e & (MT - 1), n = e >> LOG2MT;
            ob[(size_t)n * OROWS + r] = lds[r * (N + 4) + n];
        }
    } else {
        float* ob = out + (size_t)b * OBOFF;
#pragma unroll
        for (int j = 0; j < WR; j++) {
            int row = r0w + sg * WR + j;
            *(float4*)(ob + (size_t)row * N + n0) = res[j];
        }
    }
}

// ---- fused logits + gumbel-softmax(hard) selection. grid 32 (b), block 256. ----
__global__ __launch_bounds__(256) void logits_select(
    const float* __restrict__ O6, const float* __restrict__ Wr,
    const float* __restrict__ br, float* __restrict__ sel_w, int* __restrict__ sel_r) {
    int b = blockIdx.x, t = threadIdx.x;
    __shared__ float sO6[128 * 68];
    __shared__ float red[4][8];
    const float4* ob4 = (const float4*)(O6 + (size_t)b * 8192);
    for (int i4 = t; i4 < 2048; i4 += 256) {
        float4 v = ob4[i4];
        int p = i4 * 4;
        int h = p >> 6, l4 = p & 63;
        *(float4*)(&sO6[h * 68 + l4]) = v;
    }
    __syncthreads();
    float acc[8] = {0, 0, 0, 0, 0, 0, 0, 0};
#pragma unroll 4
    for (int q = 0; q < 32; q++) {
        int i = q * 256 + t;
        int l4 = i >> 7, h = i & 127;
        float v = sO6[h * 68 + l4];
        const float4* wr = (const float4*)(Wr + (size_t)i * 8);
        float4 w0 = wr[0], w1 = wr[1];
        acc[0] += v * w0.x; acc[1] += v * w0.y; acc[2] += v * w0.z; acc[3] += v * w0.w;
        acc[4] += v * w1.x; acc[5] += v * w1.y; acc[6] += v * w1.z; acc[7] += v * w1.w;
    }
#pragma unroll
    for (int j = 0; j < 8; j++)
#pragma unroll
        for (int off = 32; off > 0; off >>= 1) acc[j] += __shfl_xor(acc[j], off, 64);
    int lane = t & 63, wid = t >> 6;
    if (lane == 0)
        for (int j = 0; j < 8; j++) red[wid][j] = acc[j];
    __syncthreads();
    if (t == 0) {
        float z[8];
        for (int j = 0; j < 8; j++) {
            float lg = br[j] + red[0][j] + red[1][j] + red[2][j] + red[3][j];
            z[j] = lg + gumbel_at(b * 8 + j);
        }
        int am = 0;
        float zm = z[0];
        for (int j = 1; j < 8; j++)
            if (z[j] > zm) { zm = z[j]; am = j; }
        float ssum = 0.f;
        for (int j = 0; j < 8; j++) ssum += expf(z[j] - zm);
        float s = 1.0f / ssum;
        sel_w[b] = (1.0f - s) + s;
        sel_r[b] = am;
    }
}

// ---- regime-grouped einsum v3 (round-3): float4 proto reads, low VGPR,
// in-wave rowgroup reduce. grid (128 n, 8 r, 2 hz), block 192. ----
__global__ __launch_bounds__(192, 4) void einsum_nsplit(
    const float* __restrict__ e_st, const float* __restrict__ proto,
    const int* __restrict__ sel_r, float* __restrict__ part) {
    const int n = blockIdx.x, r = blockIdx.y, hz = blockIdx.z, t = threadIdx.x;
    const int w = t >> 6, ln = t & 63;
    const int rg = ln >> 4;
    const int q4 = (w * 16 + (ln & 15)) * 4;
    __shared__ int loc[32];
    __shared__ int s_gs;
    if (t == 0) {
        int g = 0;
        for (int bb = 0; bb < 32; bb++)
            if (sel_r[bb] == r) loc[g++] = bb;
        s_gs = g;
    }
    __syncthreads();
    const int gs = s_gs;
    if (gs == 0) return;
    __shared__ __align__(16) float es[64][12];
    const float* pb = proto + (((size_t)r * 128 + n) * 128 + hz * 64) * 192;
    float* po = part + (size_t)hz * (32 * 128 * 192);
    for (int s0 = 0; s0 < gs; s0 += 8) {
        int np = gs - s0 < 8 ? gs - s0 : 8;
        __syncthreads();
        for (int i = t; i < 512; i += 192) {
            int sb = i >> 6, h = i & 63;
            float v = 0.f;
            if (sb < np)
                v = e_st[((size_t)loc[s0 + sb] * 128 + n) * 128 + hz * 64 + h];
            es[h][sb] = v;
        }
        __syncthreads();
        float4 a[8];
#pragma unroll
        for (int sb = 0; sb < 8; sb++) a[sb] = make_float4(0.f, 0.f, 0.f, 0.f);
#pragma unroll 4
        for (int hh = 0; hh < 16; hh++) {
            int row = hh * 4 + rg;
            float4 pv = *(const float4*)(pb + (size_t)row * 192 + q4);
            float4 e0 = *(const float4*)(&es[row][0]);
            float4 e1 = *(const float4*)(&es[row][4]);
#define ACC4(j, s) a[j].x += (s) * pv.x; a[j].y += (s) * pv.y; \
                   a[j].z += (s) * pv.z; a[j].w += (s) * pv.w;
            ACC4(0, e0.x) ACC4(1, e0.y) ACC4(2, e0.z) ACC4(3, e0.w)
            ACC4(4, e1.x) ACC4(5, e1.y) ACC4(6, e1.z) ACC4(7, e1.w)
#undef ACC4
        }
#pragma unroll
        for (int sb = 0; sb < 8; sb++) {
            a[sb].x += __shfl_xor(a[sb].x, 16, 64);
            a[sb].y += __shfl_xor(a[sb].y, 16, 64);
            a[sb].z += __shfl_xor(a[sb].z, 16, 64);
            a[sb].w += __shfl_xor(a[sb].w, 16, 64);
            a[sb].x += __shfl_xor(a[sb].x, 32, 64);
            a[sb].y += __shfl_xor(a[sb].y, 32, 64);
            a[sb].z += __shfl_xor(a[sb].z, 32, 64);
            a[sb].w += __shfl_xor(a[sb].w, 32, 64);
        }
        if (ln < 16) {
#pragma unroll
            for (int sb = 0; sb < 8; sb++) {
                if (sb < np) {
                    int bb = loc[s0 + sb];
                    *(float4*)(po + ((size_t)bb * 128 + n) * 192 + q4) = a[sb];
                }
            }
        }
    }
}

// ---- reduce 2x128 n-partials, scale by regime weight, softmax over 192 ----
__global__ void finalize_kernel(const float* __restrict__ part, const float* __restrict__ sel_w,
                                float* __restrict__ out) {
    int b = blockIdx.x, t = threadIdx.x;
    __shared__ float red[4];
    const float* p0 = part + (size_t)b * 128 * 192 + t;
    const float* p1 = p0 + (size_t)32 * 128 * 192;
    float v = 0.f;
#pragma unroll 8
    for (int c = 0; c < 128; c++) {
        v += p0[(size_t)c * 192];
        v += p1[(size_t)c * 192];
    }
    v *= sel_w[b];
    float mx = block_max(v, red);
    float e = expf(v - mx);
    float s = block_sum(e, red);
    out[(size_t)b * 192 + t] = e / s;
}

extern "C" void kernel_launch(void* const* d_in, const int* in_sizes, int n_in,
                              void* d_out, int out_size, void* d_ws, size_t ws_size,
                              hipStream_t stream) {
    const float* in_lt = (const float*)d_in[0];
    const float* in_st = (const float*)d_in[1];
    const float* Ws  = (const float*)d_in[2];  const float* bs  = (const float*)d_in[3];
    const float* Wt  = (const float*)d_in[4];  const float* bt  = (const float*)d_in[5];
    const float* Wh1 = (const float*)d_in[6];  const float* bh1 = (const float*)d_in[7];
    const float* Wl1 = (const float*)d_in[8];  const float* bl1 = (const float*)d_in[9];
    const float* Wh2 = (const float*)d_in[10]; const float* bh2 = (const float*)d_in[11];
    const float* Wl2 = (const float*)d_in[12]; const float* bl2 = (const float*)d_in[13];
    const float* Wh3 = (const float*)d_in[14]; const float* bh3 = (const float*)d_in[15];
    const float* Wl3 = (const float*)d_in[16]; const float* bl3 = (const float*)d_in[17];
    const float* Wr  = (const float*)d_in[18]; const float* br  = (const float*)d_in[19];
    const float* proto = (const float*)d_in[20];
    float* out = (float*)d_out;

    float* ws = (float*)d_ws;
    size_t off = 0;
    float* e_lt = ws + off; off += (size_t)32 * 512 * 128;   // [(b,l)][h]
    float* e_st = ws + off; off += (size_t)32 * 128 * 128;   // [b,n][h]
    float* O1T = ws + off; off += (size_t)128 * 16384;       // [h][(b,l)]
    float* O2T = ws + off; off += (size_t)256 * 4096;        // [l2][(b,h)]
    float* O3T = ws + off; off += (size_t)128 * 8192;        // [h][(b,l2)]
    float* O4T = ws + off; off += (size_t)128 * 4096;        // [l3][(b,h)]
    float* O5T = ws + off; off += (size_t)128 * 4096;        // [h][(b,l3)]
    float* O6 = ws + off; off += (size_t)32 * 128 * 64;      // [b][h][l4]
    float* part = ws + off; off += (size_t)2 * 32 * 128 * 192;  // [hz][b][n][t]
    float* sel_w = ws + off; off += 32;
    int* sel_r = (int*)(ws + off); off += 32;

    // ======================= DIAGNOSTIC ROUND =======================
    // The full 9-kernel pipeline is executed TWICE. All kernels are pure
    // (threefry is counter-based; pass 2 recomputes byte-identical values),
    // so passed/absmax are unaffected. Purpose: K = dur_us - 323 gives the
    // true summed kernel time, splitting it from the fixed harness cost
    // that 5 rounds of bottom-up modeling failed to close.
    // ================================================================
    for (int pass = 0; pass < 2; pass++) {
        encode_kernel<<<dim3(160, 32), 256, 0, stream>>>(in_lt, in_st, Ws, bs, Wt, bt, e_lt, e_st);
        lbr_wave<128, 128, 2, 64, true><<<dim3(1024, 1), 256, 0, stream>>>(
            e_lt, 128, 0, Wh1, bh1, O1T, 16384, 0);
        lbr_wave<512, 256, 4, 64, true><<<dim3(8, 32), 256, 0, stream>>>(
            O1T, 16384, 512, Wl1, bl1, O2T, 4096, 128);
        lbr_wave<128, 128, 2, 64, true><<<dim3(16, 32), 256, 0, stream>>>(
            O2T, 4096, 128, Wh2, bh2, O3T, 8192, 256);
        lbr_wave<256, 128, 1, 64, true><<<dim3(16, 32), 256, 0, stream>>>(
            O3T, 8192, 256, Wl2, bl2, O4T, 4096, 128);
        lbr_wave<128, 128, 1, 64, true><<<dim3(16, 32), 256, 0, stream>>>(
            O4T, 4096, 128, Wh3, bh3, O5T, 4096, 128);
        lbr_wave<128, 64, 1, 128, false><<<dim3(8, 32), 256, 0, stream>>>(
            O5T, 4096, 128, Wl3, bl3, O6, 0, 8192);
        logits_select<<<32, 256, 0, stream>>>(O6, Wr, br, sel_w, sel_r);
        einsum_nsplit<<<dim3(128, 8, 2), 192, 0, stream>>>(e_st, proto, sel_r, part);
        finalize_kernel<<<32, 192, 0, stream>>>(part, sel_w, out);
    }
}

// Round 11
// 320.641 us; speedup vs baseline: 1.4518x; 1.4518x over previous
//
#include <hip/hip_runtime.h>
#include <math.h>

#define EPS 1e-5f

__device__ __forceinline__ float gelu_exact(float x) {
    return 0.5f * x * (1.0f + erff(x * 0.7071067811865476f));
}

// ---- block reductions for finalize (192 threads = 3 waves) ----
__device__ float block_sum(float v, float* red) {
    int lane = threadIdx.x & 63, wid = threadIdx.x >> 6;
#pragma unroll
    for (int off = 32; off > 0; off >>= 1) v += __shfl_down(v, off, 64);
    if (lane == 0) red[wid] = v;
    __syncthreads();
    int nw = ((int)blockDim.x + 63) >> 6;
    float s = red[0];
    for (int w = 1; w < nw; w++) s += red[w];
    __syncthreads();
    return s;
}

__device__ float block_max(float v, float* red) {
    int lane = threadIdx.x & 63, wid = threadIdx.x >> 6;
#pragma unroll
    for (int off = 32; off > 0; off >>= 1) v = fmaxf(v, __shfl_down(v, off, 64));
    if (lane == 0) red[wid] = v;
    __syncthreads();
    int nw = ((int)blockDim.x + 63) >> 6;
    float s = red[0];
    for (int w = 1; w < nw; w++) s = fmaxf(s, red[w]);
    __syncthreads();
    return s;
}

// ---- threefry2x32-20 (JAX PRNG), partitionable scheme (verified round 1) ----
__device__ void threefry2x32(unsigned k0, unsigned k1, unsigned x0, unsigned x1,
                             unsigned& o0, unsigned& o1) {
    unsigned ks[3] = {k0, k1, k0 ^ k1 ^ 0x1BD11BDAu};
    const unsigned rot[2][4] = {{13u, 15u, 26u, 6u}, {17u, 29u, 16u, 24u}};
    x0 += ks[0]; x1 += ks[1];
#pragma unroll
    for (int i = 0; i < 5; i++) {
#pragma unroll
        for (int j = 0; j < 4; j++) {
            unsigned r = rot[i & 1][j];
            x0 += x1;
            x1 = (x1 << r) | (x1 >> (32 - r));
            x1 ^= x0;
        }
        x0 += ks[(i + 1) % 3];
        x1 += ks[(i + 2) % 3] + (unsigned)(i + 1);
    }
    o0 = x0; o1 = x1;
}

__device__ float gumbel_at(int j) {
    unsigned o0, o1;
    threefry2x32(0u, 42u, 0u, (unsigned)j, o0, o1);
    unsigned bits = o0 ^ o1;
    float f = __uint_as_float((bits >> 9) | 0x3F800000u) - 1.0f;  // [0,1)
    float u = fmaxf(f + 1.17549435e-38f, 1.17549435e-38f);
    return -logf(-logf(u));
}

// ---- encode16: 16 rows per block with a SHARED 40x9 window (10x less
// gather redundancy than 1-row-per-wave; E-phase math verified in R6).
// Blocks [0,1024): lt (b=bx>>5, l0=(bx&31)*16); [1024,1280): st. ----
__global__ __launch_bounds__(256) void encode16_kernel(
    const float* __restrict__ x_lt, const float* __restrict__ x_st,
    const float* __restrict__ Ws, const float* __restrict__ bs,
    const float* __restrict__ Wt, const float* __restrict__ bt,
    float* __restrict__ e_lt, float* __restrict__ e_st) {
    __shared__ float xwin[40 * 9];
    __shared__ float x0s[9];
    __shared__ float smS[16 * 9], smT[16 * 9];
    const int t = threadIdx.x;
    const int w = t >> 6, ln = t & 63;
    const int bx = blockIdx.x;
    const bool st = bx >= 1024;
    int b, l0, L;
    const float* xb;
    float* e;
    if (st) {
        int ub = bx - 1024;
        b = ub >> 3; l0 = (ub & 7) * 16; L = 128;
        xb = x_st + (size_t)b * 128 * 9;
        e = e_st;
    } else {
        b = bx >> 5; l0 = (bx & 31) * 16; L = 512;
        xb = x_lt + (size_t)b * 512 * 9;
        e = e_lt;
    }
    // E1: stage window rows l0-12 .. l0+27 (edge-clamped)
    for (int f = t; f < 360; f += 256) {
        int row = f / 9, c = f - row * 9;
        int rr = l0 - 12 + row;
        rr = rr < 0 ? 0 : (rr > L - 1 ? L - 1 : rr);
        xwin[f] = xb[(size_t)rr * 9 + c];
    }
    if (t < 9) x0s[t] = xb[t];
    __syncthreads();
    // E2: moving average + seasonal split, 16 l x 9 ch
    if (t < 144) {
        int li = t / 9, c = t - (t / 9) * 9;
        float s = 0.f;
#pragma unroll
        for (int j = 0; j < 25; j++) s += xwin[(li + j) * 9 + c];
        float x0 = x0s[c];
        float mm = (s - 25.f * x0) * (1.0f / 25.0f);
        smS[t] = (xwin[(li + 12) * 9 + c] - x0) - mm;
        smT[t] = mm;
    }
    __syncthreads();
    // E3: LBR-encode; each wave does 4 rows (2 h per lane)
    for (int q = 0; q < 4; q++) {
        int li = w * 4 + q;
        const float* sS = smS + li * 9;
        const float* sT = smT + li * 9;
        float ysA = bs[ln], ysB = bs[ln + 64];
        float ytA = bt[ln], ytB = bt[ln + 64];
#pragma unroll
        for (int c = 0; c < 9; c++) {
            float sv = sS[c], mv = sT[c];
            ysA += sv * Ws[c * 128 + ln];
            ysB += sv * Ws[c * 128 + ln + 64];
            ytA += mv * Wt[c * 128 + ln];
            ytB += mv * Wt[c * 128 + ln + 64];
        }
        float sa = ysA + ysB, sb2 = ytA + ytB;
#pragma unroll
        for (int off = 32; off > 0; off >>= 1) {
            sa += __shfl_xor(sa, off, 64);
            sb2 += __shfl_xor(sb2, off, 64);
        }
        float ms = sa * (1.0f / 128.0f), mt = sb2 * (1.0f / 128.0f);
        float dA = ysA - ms, dB = ysB - ms;
        float tA = ytA - mt, tB = ytB - mt;
        float qa = dA * dA + dB * dB, qb = tA * tA + tB * tB;
#pragma unroll
        for (int off = 32; off > 0; off >>= 1) {
            qa += __shfl_xor(qa, off, 64);
            qb += __shfl_xor(qb, off, 64);
        }
        float inva = rsqrtf(qa * (1.0f / 128.0f) + EPS);
        float invb = rsqrtf(qb * (1.0f / 128.0f) + EPS);
        float* eo = e + ((size_t)b * L + (l0 + li)) * 128;
        eo[ln] = gelu_exact(dA * inva) + gelu_exact(tA * invb);
        eo[ln + 64] = gelu_exact(dB * inva) + gelu_exact(tB * invb);
    }
}

// ---- Linear -> InstanceNorm -> GELU with BLOCK-SHARED W chunks in LDS
// (round-4 structure, 2-barrier simple staging; no dbuf per R8 lesson). ----
template <int K, int N, int WR, int KC, bool TRANS>
__global__ __launch_bounds__(256) void lbr_wave(
    const float* __restrict__ A, int S, int ABOFF,
    const float* __restrict__ W, const float* __restrict__ bias,
    float* __restrict__ out, int OROWS, int OBOFF) {
    constexpr int CG = N / 4;
    constexpr int SG = 64 / CG;
    constexpr int RW = SG * WR;
    constexpr int MT = 4 * RW;
    constexpr int LOG2MT = (MT == 8) ? 3 : ((MT == 16) ? 4 : 5);
    constexpr int WSZ = KC * N;
    constexpr int ASZ = 4 * RW * K;
    static_assert(WSZ >= MT * (N + 4) || !TRANS, "TRANS tile must fit in W region");
    static_assert((WSZ / 4) % 256 == 0, "W chunk loads must be exact");
    __shared__ __align__(16) float lds[WSZ + ASZ];
    const int t = threadIdx.x;
    const int w = t >> 6, ln = t & 63;
    const int sg = ln / CG;
    const int n0 = (ln % CG) * 4;
    const int b = blockIdx.y;
    const int r0b = blockIdx.x * MT;
    const int r0w = r0b + w * RW;
    float* Wl = lds;
    float* As = lds + WSZ + w * RW * K;
    const float* Ab = A + (size_t)b * ABOFF;
    for (int idx = ln; idx < RW * (K / 4); idx += 64) {
        int rr = idx / (K / 4), kk = idx % (K / 4);
        float4 v = *(const float4*)(Ab + (size_t)(r0w + rr) * S + kk * 4);
        *(float4*)(As + rr * K + kk * 4) = v;
    }
    float4 acc[WR];
    {
        float4 bv = *(const float4*)(bias + n0);
#pragma unroll
        for (int j = 0; j < WR; j++) acc[j] = bv;
    }
    const float* ap = As + (sg * WR) * K;
    for (int kc0 = 0; kc0 < K; kc0 += KC) {
        __syncthreads();
        {
            const float4* wg = (const float4*)(W + (size_t)kc0 * N);
            float4* wl4 = (float4*)Wl;
#pragma unroll
            for (int i = 0; i < WSZ / 4 / 256; i++)
                wl4[t + i * 256] = wg[t + i * 256];
        }
        __syncthreads();
#pragma unroll 2
        for (int k = 0; k < KC; k += 4) {
            const float* wp = Wl + k * N + n0;
            float4 w0 = *(const float4*)(wp);
            float4 w1 = *(const float4*)(wp + N);
            float4 w2 = *(const float4*)(wp + 2 * N);
            float4 w3 = *(const float4*)(wp + 3 * N);
#pragma unroll
            for (int j = 0; j < WR; j++) {
                float4 a4 = *(const float4*)(ap + j * K + kc0 + k);
                acc[j].x += a4.x * w0.x; acc[j].y += a4.x * w0.y;
                acc[j].z += a4.x * w0.z; acc[j].w += a4.x * w0.w;
                acc[j].x += a4.y * w1.x; acc[j].y += a4.y * w1.y;
                acc[j].z += a4.y * w1.z; acc[j].w += a4.y * w1.w;
                acc[j].x += a4.z * w2.x; acc[j].y += a4.z * w2.y;
                acc[j].z += a4.z * w2.z; acc[j].w += a4.z * w2.w;
                acc[j].x += a4.w * w3.x; acc[j].y += a4.w * w3.y;
                acc[j].z += a4.w * w3.z; acc[j].w += a4.w * w3.w;
            }
        }
    }
    float4 res[WR];
#pragma unroll
    for (int j = 0; j < WR; j++) {
        float s = acc[j].x + acc[j].y + acc[j].z + acc[j].w;
#pragma unroll
        for (int off = CG / 2; off > 0; off >>= 1) s += __shfl_xor(s, off, 64);
        float m = s * (1.0f / (float)N);
        float dx = acc[j].x - m, dy = acc[j].y - m, dz = acc[j].z - m, dw = acc[j].w - m;
        float q = dx * dx + dy * dy + dz * dz + dw * dw;
#pragma unroll
        for (int off = CG / 2; off > 0; off >>= 1) q += __shfl_xor(q, off, 64);
        float inv = rsqrtf(q * (1.0f / (float)N) + EPS);
        res[j].x = gelu_exact(dx * inv);
        res[j].y = gelu_exact(dy * inv);
        res[j].z = gelu_exact(dz * inv);
        res[j].w = gelu_exact(dw * inv);
    }
    if constexpr (TRANS) {
        __syncthreads();
#pragma unroll
        for (int j = 0; j < WR; j++) {
            int rl = w * RW + sg * WR + j;
            *(float4*)(lds + rl * (N + 4) + n0) = res[j];
        }
        __syncthreads();
        float* ob = out + (size_t)b * OBOFF + r0b;
        for (int e = t; e < MT * N; e += 256) {
            int r = e & (MT - 1), n = e >> LOG2MT;
            ob[(size_t)n * OROWS + r] = lds[r * (N + 4) + n];
        }
    } else {
        float* ob = out + (size_t)b * OBOFF;
#pragma unroll
        for (int j = 0; j < WR; j++) {
            int row = r0w + sg * WR + j;
            *(float4*)(ob + (size_t)row * N + n0) = res[j];
        }
    }
}

// ---- fused logits + gumbel-softmax(hard) selection. grid 32 (b), block 256. ----
__global__ __launch_bounds__(256) void logits_select(
    const float* __restrict__ O6, const float* __restrict__ Wr,
    const float* __restrict__ br, float* __restrict__ sel_w, int* __restrict__ sel_r) {
    int b = blockIdx.x, t = threadIdx.x;
    __shared__ float sO6[128 * 68];
    __shared__ float red[4][8];
    const float4* ob4 = (const float4*)(O6 + (size_t)b * 8192);
    for (int i4 = t; i4 < 2048; i4 += 256) {
        float4 v = ob4[i4];
        int p = i4 * 4;
        int h = p >> 6, l4 = p & 63;
        *(float4*)(&sO6[h * 68 + l4]) = v;
    }
    __syncthreads();
    float acc[8] = {0, 0, 0, 0, 0, 0, 0, 0};
#pragma unroll 4
    for (int q = 0; q < 32; q++) {
        int i = q * 256 + t;
        int l4 = i >> 7, h = i & 127;
        float v = sO6[h * 68 + l4];
        const float4* wr = (const float4*)(Wr + (size_t)i * 8);
        float4 w0 = wr[0], w1 = wr[1];
        acc[0] += v * w0.x; acc[1] += v * w0.y; acc[2] += v * w0.z; acc[3] += v * w0.w;
        acc[4] += v * w1.x; acc[5] += v * w1.y; acc[6] += v * w1.z; acc[7] += v * w1.w;
    }
#pragma unroll
    for (int j = 0; j < 8; j++)
#pragma unroll
        for (int off = 32; off > 0; off >>= 1) acc[j] += __shfl_xor(acc[j], off, 64);
    int lane = t & 63, wid = t >> 6;
    if (lane == 0)
        for (int j = 0; j < 8; j++) red[wid][j] = acc[j];
    __syncthreads();
    if (t == 0) {
        float z[8];
        for (int j = 0; j < 8; j++) {
            float lg = br[j] + red[0][j] + red[1][j] + red[2][j] + red[3][j];
            z[j] = lg + gumbel_at(b * 8 + j);
        }
        int am = 0;
        float zm = z[0];
        for (int j = 1; j < 8; j++)
            if (z[j] > zm) { zm = z[j]; am = j; }
        float ssum = 0.f;
        for (int j = 0; j < 8; j++) ssum += expf(z[j] - zm);
        float s = 1.0f / ssum;
        sel_w[b] = (1.0f - s) + s;
        sel_r[b] = am;
    }
}

// ---- regime-grouped einsum v3 (round-3): float4 proto reads, low VGPR,
// in-wave rowgroup reduce. grid (128 n, 8 r, 2 hz), block 192. ----
__global__ __launch_bounds__(192, 4) void einsum_nsplit(
    const float* __restrict__ e_st, const float* __restrict__ proto,
    const int* __restrict__ sel_r, float* __restrict__ part) {
    const int n = blockIdx.x, r = blockIdx.y, hz = blockIdx.z, t = threadIdx.x;
    const int w = t >> 6, ln = t & 63;
    const int rg = ln >> 4;
    const int q4 = (w * 16 + (ln & 15)) * 4;
    __shared__ int loc[32];
    __shared__ int s_gs;
    if (t == 0) {
        int g = 0;
        for (int bb = 0; bb < 32; bb++)
            if (sel_r[bb] == r) loc[g++] = bb;
        s_gs = g;
    }
    __syncthreads();
    const int gs = s_gs;
    if (gs == 0) return;
    __shared__ __align__(16) float es[64][12];
    const float* pb = proto + (((size_t)r * 128 + n) * 128 + hz * 64) * 192;
    float* po = part + (size_t)hz * (32 * 128 * 192);
    for (int s0 = 0; s0 < gs; s0 += 8) {
        int np = gs - s0 < 8 ? gs - s0 : 8;
        __syncthreads();
        for (int i = t; i < 512; i += 192) {
            int sb = i >> 6, h = i & 63;
            float v = 0.f;
            if (sb < np)
                v = e_st[((size_t)loc[s0 + sb] * 128 + n) * 128 + hz * 64 + h];
            es[h][sb] = v;
        }
        __syncthreads();
        float4 a[8];
#pragma unroll
        for (int sb = 0; sb < 8; sb++) a[sb] = make_float4(0.f, 0.f, 0.f, 0.f);
#pragma unroll 4
        for (int hh = 0; hh < 16; hh++) {
            int row = hh * 4 + rg;
            float4 pv = *(const float4*)(pb + (size_t)row * 192 + q4);
            float4 e0 = *(const float4*)(&es[row][0]);
            float4 e1 = *(const float4*)(&es[row][4]);
#define ACC4(j, s) a[j].x += (s) * pv.x; a[j].y += (s) * pv.y; \
                   a[j].z += (s) * pv.z; a[j].w += (s) * pv.w;
            ACC4(0, e0.x) ACC4(1, e0.y) ACC4(2, e0.z) ACC4(3, e0.w)
            ACC4(4, e1.x) ACC4(5, e1.y) ACC4(6, e1.z) ACC4(7, e1.w)
#undef ACC4
        }
#pragma unroll
        for (int sb = 0; sb < 8; sb++) {
            a[sb].x += __shfl_xor(a[sb].x, 16, 64);
            a[sb].y += __shfl_xor(a[sb].y, 16, 64);
            a[sb].z += __shfl_xor(a[sb].z, 16, 64);
            a[sb].w += __shfl_xor(a[sb].w, 16, 64);
            a[sb].x += __shfl_xor(a[sb].x, 32, 64);
            a[sb].y += __shfl_xor(a[sb].y, 32, 64);
            a[sb].z += __shfl_xor(a[sb].z, 32, 64);
            a[sb].w += __shfl_xor(a[sb].w, 32, 64);
        }
        if (ln < 16) {
#pragma unroll
            for (int sb = 0; sb < 8; sb++) {
                if (sb < np) {
                    int bb = loc[s0 + sb];
                    *(float4*)(po + ((size_t)bb * 128 + n) * 192 + q4) = a[sb];
                }
            }
        }
    }
}

// ---- reduce 2x128 n-partials, scale by regime weight, softmax over 192 ----
__global__ void finalize_kernel(const float* __restrict__ part, const float* __restrict__ sel_w,
                                float* __restrict__ out) {
    int b = blockIdx.x, t = threadIdx.x;
    __shared__ float red[4];
    const float* p0 = part + (size_t)b * 128 * 192 + t;
    const float* p1 = p0 + (size_t)32 * 128 * 192;
    float v = 0.f;
#pragma unroll 8
    for (int c = 0; c < 128; c++) {
        v += p0[(size_t)c * 192];
        v += p1[(size_t)c * 192];
    }
    v *= sel_w[b];
    float mx = block_max(v, red);
    float e = expf(v - mx);
    float s = block_sum(e, red);
    out[(size_t)b * 192 + t] = e / s;
}

extern "C" void kernel_launch(void* const* d_in, const int* in_sizes, int n_in,
                              void* d_out, int out_size, void* d_ws, size_t ws_size,
                              hipStream_t stream) {
    const float* in_lt = (const float*)d_in[0];
    const float* in_st = (const float*)d_in[1];
    const float* Ws  = (const float*)d_in[2];  const float* bs  = (const float*)d_in[3];
    const float* Wt  = (const float*)d_in[4];  const float* bt  = (const float*)d_in[5];
    const float* Wh1 = (const float*)d_in[6];  const float* bh1 = (const float*)d_in[7];
    const float* Wl1 = (const float*)d_in[8];  const float* bl1 = (const float*)d_in[9];
    const float* Wh2 = (const float*)d_in[10]; const float* bh2 = (const float*)d_in[11];
    const float* Wl2 = (const float*)d_in[12]; const float* bl2 = (const float*)d_in[13];
    const float* Wh3 = (const float*)d_in[14]; const float* bh3 = (const float*)d_in[15];
    const float* Wl3 = (const float*)d_in[16]; const float* bl3 = (const float*)d_in[17];
    const float* Wr  = (const float*)d_in[18]; const float* br  = (const float*)d_in[19];
    const float* proto = (const float*)d_in[20];
    float* out = (float*)d_out;

    float* ws = (float*)d_ws;
    size_t off = 0;
    float* e_lt = ws + off; off += (size_t)32 * 512 * 128;   // [(b,l)][h]
    float* e_st = ws + off; off += (size_t)32 * 128 * 128;   // [b,n][h]
    float* O1T = ws + off; off += (size_t)128 * 16384;       // [h][(b,l)]
    float* O2T = ws + off; off += (size_t)256 * 4096;        // [l2][(b,h)]
    float* O3T = ws + off; off += (size_t)128 * 8192;        // [h][(b,l2)]
    float* O4T = ws + off; off += (size_t)128 * 4096;        // [l3][(b,h)]
    float* O5T = ws + off; off += (size_t)128 * 4096;        // [h][(b,l3)]
    float* O6 = ws + off; off += (size_t)32 * 128 * 64;      // [b][h][l4]
    float* part = ws + off; off += (size_t)2 * 32 * 128 * 192;  // [hz][b][n][t]
    float* sel_w = ws + off; off += 32;
    int* sel_r = (int*)(ws + off); off += 32;

    // encode16: 16 rows/block shared window; lt blocks [0,1024), st [1024,1280)
    encode16_kernel<<<dim3(1280), 256, 0, stream>>>(in_lt, in_st, Ws, bs, Wt, bt, e_lt, e_st);
    // h1 (round-11 change): WR=4 (MT=32), KC=64, grid 512 (2 blk/CU, 48KB) —
    // halves W LDS traffic per FLOP at the one layer with healthy occupancy
    lbr_wave<128, 128, 4, 64, true><<<dim3(512, 1), 256, 0, stream>>>(
        e_lt, 128, 0, Wh1, bh1, O1T, 16384, 0);
    // l1: WR=4, KC=64, grid (8,32)=256 (R9, neutral-at-worst, keeps 96KB LDS)
    lbr_wave<512, 256, 4, 64, true><<<dim3(8, 32), 256, 0, stream>>>(
        O1T, 16384, 512, Wl1, bl1, O2T, 4096, 128);
    // h2: rows=l2(256)/b, K=128, N=128; WR=2 (MT=16), KC=64, grid 512
    lbr_wave<128, 128, 2, 64, true><<<dim3(16, 32), 256, 0, stream>>>(
        O2T, 4096, 128, Wh2, bh2, O3T, 8192, 256);
    // l2: rows=h(128)/b, K=256, N=128; WR=1 (MT=8), KC=64, grid 512
    lbr_wave<256, 128, 1, 64, true><<<dim3(16, 32), 256, 0, stream>>>(
        O3T, 8192, 256, Wl2, bl2, O4T, 4096, 128);
    // h3: rows=l3(128)/b, K=128, N=128; WR=1 (MT=8), KC=64, grid 512
    lbr_wave<128, 128, 1, 64, true><<<dim3(16, 32), 256, 0, stream>>>(
        O4T, 4096, 128, Wh3, bh3, O5T, 4096, 128);
    // l3: rows=h(128)/b, K=128, N=64; WR=1 (MT=16), KC=128 (whole W, 32 KB)
    lbr_wave<128, 64, 1, 128, false><<<dim3(8, 32), 256, 0, stream>>>(
        O5T, 4096, 128, Wl3, bl3, O6, 0, 8192);
    logits_select<<<32, 256, 0, stream>>>(O6, Wr, br, sel_w, sel_r);
    einsum_nsplit<<<dim3(128, 8, 2), 192, 0, stream>>>(e_st, proto, sel_r, part);
    finalize_kernel<<<32, 192, 0, stream>>>(part, sel_w, out);
}